// Round 5
// baseline (486.844 us; speedup 1.0000x reference)
//
#include <hip/hip_runtime.h>
#include <cstdint>
#include <cstddef>

#define N_USERS   100000
#define N_NODES   500000
#define DIM       64
#define N_EDGES   2000000
#define BATCH     4096
#define SCAN_B    1024
#define NBLK      ((N_NODES + SCAN_B - 1) / SCAN_B)   // 489
#define X1C_CAP   280000   // |fB| ~230k measured
#define LA_CAP    100000   // |fA| ~60k measured
#define EDG4_BLK  ((N_EDGES / 4 + 255) / 256)         // 1954 blocks, 4 edges/thread
#define CONV_BLK  ((N_NODES * 16 + 255) / 256)        // 31250 conv blocks
#define CS_TOTAL  (EDG4_BLK * 17)                     // 33218: 1 scatter per 16 conv
#define PROP_BLK  2048                                // 8192 waves = 32/CU

// ---- LDS histogram geometry (no global atomics) ----
#define RANGES    31
#define RANGE_SZ  16384                               // nodes per range
#define RANGE_TOT (RANGES * RANGE_SZ)                 // 507904 >= N_NODES
#define HSLICES   8
#define HIST_BLK  (RANGES * HSLICES)                  // 248
#define ESLICE    (N_EDGES / HSLICES)                 // 250000
#define EINT4     (ESLICE / 4)                        // 62500

typedef unsigned char uchar;
typedef unsigned short ushort;
typedef unsigned int uint;

__device__ __forceinline__ ushort f2bf(float f) {
    uint u = __float_as_uint(f);
    uint r = u + 0x7FFFu + ((u >> 16) & 1u);
    return (ushort)(r >> 16);
}
__device__ __forceinline__ float bflo(uint u) { return __uint_as_float(u << 16); }
__device__ __forceinline__ float bfhi(uint u) { return __uint_as_float(u & 0xFFFF0000u); }

// ---------- mark batch indices into three byte flags ------------------------
__global__ void k_mark(const int* __restrict__ u, const int* __restrict__ p,
                       const int* __restrict__ n, uchar* __restrict__ f3,
                       uchar* __restrict__ fA, uchar* __restrict__ fB) {
    int i = blockIdx.x * blockDim.x + threadIdx.x;
    if (i >= 3 * BATCH) return;
    int idx;
    if (i < BATCH)          idx = u[i];
    else if (i < 2 * BATCH) idx = p[i - BATCH];
    else                    idx = n[i - 2 * BATCH];
    f3[idx] = 1; fA[idx] = 1; fB[idx] = 1;
}

// ---------- fused: LDS-range histogram + f3 -> fA expansion -----------------
// Global atomics measured at a fixed ~23 G ops/s with 32 B/op write-through
// (R1 device-scope == R4 per-XCD workgroup-scope: both 88-90 us, WRITE 64 MB).
// So: histogram via 31 node-ranges x 16384, 16-bit counters packed in 32 KB
// LDS; 8 edge-slices; partial counts written with PLAIN coalesced stores to
// degp16[slice] (fully overwritten -> no memset needed). scanA sums 8 copies.
// Expansion blocks (independent byte-gather work) interleave for overlap.
__global__ void k_histexp(const int* __restrict__ src, const int* __restrict__ dst,
                          ushort* __restrict__ degp16, const uchar* __restrict__ f3,
                          uchar* __restrict__ fA) {
    __shared__ uint cnt[RANGE_SZ / 2];            // 8192 words = 32 KB
    if (blockIdx.x < HIST_BLK) {
        int r = blockIdx.x >> 3;                  // range 0..30
        int s = blockIdx.x & 7;                   // slice 0..7
        for (int k = threadIdx.x; k < RANGE_SZ / 2; k += 256) cnt[k] = 0;
        __syncthreads();
        int base = r * RANGE_SZ;
        const int4* d4 = (const int4*)(dst + s * ESLICE);
        for (int t = threadIdx.x; t < EINT4; t += 256) {
            int4 d = d4[t];
            int l;
            l = d.x - base; if ((uint)l < RANGE_SZ) atomicAdd(&cnt[l >> 1], 1u << ((l & 1) << 4));
            l = d.y - base; if ((uint)l < RANGE_SZ) atomicAdd(&cnt[l >> 1], 1u << ((l & 1) << 4));
            l = d.z - base; if ((uint)l < RANGE_SZ) atomicAdd(&cnt[l >> 1], 1u << ((l & 1) << 4));
            l = d.w - base; if ((uint)l < RANGE_SZ) atomicAdd(&cnt[l >> 1], 1u << ((l & 1) << 4));
        }
        __syncthreads();
        uint* out = (uint*)degp16 + (size_t)s * (RANGE_TOT / 2) + r * (RANGE_SZ / 2);
        for (int k = threadIdx.x; k < RANGE_SZ / 2; k += 256) out[k] = cnt[k];
    } else {
        int t = (blockIdx.x - HIST_BLK) * blockDim.x + threadIdx.x;
        if (t < N_EDGES / 4) {
            int4 s0 = ((const int4*)src)[t];
            int4 d0 = ((const int4*)dst)[t];
            if (f3[d0.x] && !fA[s0.x]) fA[s0.x] = 1;
            if (f3[d0.y] && !fA[s0.y]) fA[s0.y] = 1;
            if (f3[d0.z] && !fA[s0.z]) fA[s0.z] = 1;
            if (f3[d0.w] && !fA[s0.w]) fA[s0.w] = 1;
        }
    }
}

// ---------- expand fA -> fB (dedup writes, 4 edges/thread) ------------------
__global__ void k_expand(const int* __restrict__ src, const int* __restrict__ dst,
                         const uchar* __restrict__ fin, uchar* __restrict__ fout) {
    int t = blockIdx.x * blockDim.x + threadIdx.x;
    if (t < N_EDGES / 4) {
        int4 s0 = ((const int4*)src)[t];
        int4 d0 = ((const int4*)dst)[t];
        if (fin[d0.x] && !fout[s0.x]) fout[s0.x] = 1;
        if (fin[d0.y] && !fout[s0.y]) fout[s0.y] = 1;
        if (fin[d0.z] && !fout[s0.z]) fout[s0.z] = 1;
        if (fin[d0.w] && !fout[s0.w]) fout[s0.w] = 1;
    }
}

// ---------- scan A: reduce 8 degp16 copies -> degsum; block sums ------------
__global__ void k_scanA(const ushort* __restrict__ degp16, const uchar* __restrict__ fA,
                        const uchar* __restrict__ fB, int* __restrict__ degsum,
                        int* __restrict__ bsumD, int* __restrict__ bsumP) {
    __shared__ int sD[SCAN_B];
    __shared__ int sP[SCAN_B];
    int i = blockIdx.x * SCAN_B + threadIdx.x;
    int d = 0, pk = 0;
    if (i < N_NODES) {
        #pragma unroll
        for (int s = 0; s < HSLICES; ++s) d += (int)degp16[(size_t)s * RANGE_TOT + i];
        degsum[i] = d;
        pk = (int)fA[i] | ((int)fB[i] << 16);
    }
    sD[threadIdx.x] = d; sP[threadIdx.x] = pk;
    __syncthreads();
    for (int off = SCAN_B / 2; off; off >>= 1) {
        if (threadIdx.x < off) {
            sD[threadIdx.x] += sD[threadIdx.x + off];
            sP[threadIdx.x] += sP[threadIdx.x + off];
        }
        __syncthreads();
    }
    if (threadIdx.x == 0) { bsumD[blockIdx.x] = sD[0]; bsumP[blockIdx.x] = sP[0]; }
}

// ---------- scan B: exclusive scans of block sums ---------------------------
__global__ void k_scanB(const int* __restrict__ bsumD, const int* __restrict__ bsumP,
                        int* __restrict__ boffD, int* __restrict__ boffA,
                        int* __restrict__ boffB, int* __restrict__ counts) {
    __shared__ int sD[512];
    __shared__ int sA[512];
    __shared__ int sB[512];
    int d = (threadIdx.x < NBLK) ? bsumD[threadIdx.x] : 0;
    int p = (threadIdx.x < NBLK) ? bsumP[threadIdx.x] : 0;
    int a = p & 0xFFFF, b = p >> 16;
    sD[threadIdx.x] = d; sA[threadIdx.x] = a; sB[threadIdx.x] = b;
    __syncthreads();
    for (int off = 1; off < 512; off <<= 1) {
        int tD = (threadIdx.x >= off) ? sD[threadIdx.x - off] : 0;
        int tA = (threadIdx.x >= off) ? sA[threadIdx.x - off] : 0;
        int tB = (threadIdx.x >= off) ? sB[threadIdx.x - off] : 0;
        __syncthreads();
        sD[threadIdx.x] += tD; sA[threadIdx.x] += tA; sB[threadIdx.x] += tB;
        __syncthreads();
    }
    if (threadIdx.x < NBLK) {
        boffD[threadIdx.x] = sD[threadIdx.x] - d;
        boffA[threadIdx.x] = sA[threadIdx.x] - a;
        boffB[threadIdx.x] = sB[threadIdx.x] - b;
    }
    if (threadIdx.x == 511) { counts[0] = sA[511]; counts[1] = sB[511]; }
}

// ---------- scan C: rowstart/dinv + mapA/mapB + packed worklists ------------
__global__ void k_scanC(const int* __restrict__ degsum, const uchar* __restrict__ fA,
                        const uchar* __restrict__ fB,
                        const int* __restrict__ boffD, const int* __restrict__ boffA,
                        const int* __restrict__ boffB,
                        int* __restrict__ rowstart, float* __restrict__ dinv,
                        int* __restrict__ mapA, int* __restrict__ mapB,
                        int4* __restrict__ listA4, int4* __restrict__ listB4) {
    __shared__ int sD[SCAN_B];
    __shared__ int sP[SCAN_B];
    int i = blockIdx.x * SCAN_B + threadIdx.x;
    int d = 0, a = 0, b = 0;
    if (i < N_NODES) { d = degsum[i]; a = (int)fA[i]; b = (int)fB[i]; }
    sD[threadIdx.x] = d; sP[threadIdx.x] = a | (b << 16);
    __syncthreads();
    for (int off = 1; off < SCAN_B; off <<= 1) {
        int tD = (threadIdx.x >= off) ? sD[threadIdx.x - off] : 0;
        int tP = (threadIdx.x >= off) ? sP[threadIdx.x - off] : 0;
        __syncthreads();
        sD[threadIdx.x] += tD; sP[threadIdx.x] += tP;
        __syncthreads();
    }
    if (i < N_NODES) {
        int exD = sD[threadIdx.x] - d + boffD[blockIdx.x];
        int incP = sP[threadIdx.x];
        int exA = (incP & 0xFFFF) - a + boffA[blockIdx.x];
        int exB = (incP >> 16) - b + boffB[blockIdx.x];
        rowstart[i] = exD;
        float dv = (d > 0) ? rsqrtf((float)d) : 0.0f;
        dinv[i] = dv;
        mapA[i] = a ? exA : -1;
        mapB[i] = b ? exB : -1;
        int4 ent = make_int4(exD, exD + d, __float_as_int(dv), 0);
        if (a) listA4[exA] = ent;
        if (b) listB4[exB] = ent;
    }
}

// ---------- INTERLEAVED conv + scatter --------------------------------------
// Groups of 17 blocks: slot 8 is a scatter block, the other 16 are conv.
__global__ void k_convscatter(const float* __restrict__ emb,
                              const float* __restrict__ dinv,
                              ushort* __restrict__ embs,
                              const int* __restrict__ src, const int* __restrict__ dst,
                              const uchar* __restrict__ fB,
                              int* __restrict__ rowstart, int* __restrict__ csr_src) {
    uint b = blockIdx.x;
    uint g = b / 17u;
    uint r = b - g * 17u;
    if (r == 8u) {                       // scatter block, index g in [0, EDG4_BLK)
        int t = (int)g * blockDim.x + threadIdx.x;
        if (t < N_EDGES / 4) {
            int4 s0 = ((const int4*)src)[t];
            int4 d0 = ((const int4*)dst)[t];
            if (fB[d0.x]) csr_src[atomicAdd(&rowstart[d0.x], 1)] = s0.x;
            if (fB[d0.y]) csr_src[atomicAdd(&rowstart[d0.y], 1)] = s0.y;
            if (fB[d0.z]) csr_src[atomicAdd(&rowstart[d0.z], 1)] = s0.z;
            if (fB[d0.w]) csr_src[atomicAdd(&rowstart[d0.w], 1)] = s0.w;
        }
    } else {                             // conv block
        uint convblk = g * 16u + r - (r > 8u ? 1u : 0u);
        int c = (int)convblk * blockDim.x + threadIdx.x;   // 4-float chunk
        if (c < N_NODES * 16) {
            int row = c >> 4;
            float4 v = ((const float4*)emb)[c];
            float dv = dinv[row];
            uint2 o;
            o.x = (uint)f2bf(v.x * dv) | ((uint)f2bf(v.y * dv) << 16);
            o.y = (uint)f2bf(v.z * dv) | ((uint)f2bf(v.w * dv) << 16);
            ((uint2*)embs)[c] = o;
        }
    }
}

// ---------- layer 1: embs(bf16, pre-scaled) -> x1c(bf16, x1*dinv[node]) -----
__global__ void k_prop1(const ushort* __restrict__ embs, const int4* __restrict__ listB4,
                        const int* __restrict__ counts, const int* __restrict__ csr_src,
                        ushort* __restrict__ x1c) {
    int lane = threadIdx.x & 63;
    int sub = lane >> 4, q = lane & 15;
    int wv = (blockIdx.x * blockDim.x + threadIdx.x) >> 6;
    int nw = (gridDim.x * blockDim.x) >> 6;
    int cnt = counts[1];
    for (; wv < cnt; wv += nw) {
        int4 nb = listB4[wv];
        float4 acc = {0.f, 0.f, 0.f, 0.f};
        for (int i = nb.x + sub; i < nb.y; i += 4) {
            int s = csr_src[i];
            uint2 u = *(const uint2*)(embs + (size_t)s * DIM + q * 4);
            acc.x += bflo(u.x); acc.y += bfhi(u.x);
            acc.z += bflo(u.y); acc.w += bfhi(u.y);
        }
        for (int off = 16; off <= 32; off <<= 1) {
            acc.x += __shfl_xor(acc.x, off, 64);
            acc.y += __shfl_xor(acc.y, off, 64);
            acc.z += __shfl_xor(acc.z, off, 64);
            acc.w += __shfl_xor(acc.w, off, 64);
        }
        if (sub == 0) {
            float dv = __int_as_float(nb.z);
            float d2 = dv * dv;   // store x1*dinv[node] for next layer
            uint2 o;
            o.x = (uint)f2bf(acc.x * d2) | ((uint)f2bf(acc.y * d2) << 16);
            o.y = (uint)f2bf(acc.z * d2) | ((uint)f2bf(acc.w * d2) << 16);
            *(uint2*)(x1c + (size_t)wv * DIM + q * 4) = o;
        }
    }
}

// ---------- layer 2: x1c -> x2c (bf16, x2*dinv[node]) -----------------------
__global__ void k_prop2(const ushort* __restrict__ x1c, const int* __restrict__ mapB,
                        const int4* __restrict__ listA4, const int* __restrict__ counts,
                        const int* __restrict__ csr_src, ushort* __restrict__ x2c) {
    int lane = threadIdx.x & 63;
    int sub = lane >> 4, q = lane & 15;
    int wv = (blockIdx.x * blockDim.x + threadIdx.x) >> 6;
    int nw = (gridDim.x * blockDim.x) >> 6;
    int cnt = counts[0];
    for (; wv < cnt; wv += nw) {
        int4 nb = listA4[wv];
        float4 acc = {0.f, 0.f, 0.f, 0.f};
        for (int i = nb.x + sub; i < nb.y; i += 4) {
            int s = csr_src[i];
            int slot = mapB[s];
            uint2 u = *(const uint2*)(x1c + (size_t)slot * DIM + q * 4);
            acc.x += bflo(u.x); acc.y += bfhi(u.x);
            acc.z += bflo(u.y); acc.w += bfhi(u.y);
        }
        for (int off = 16; off <= 32; off <<= 1) {
            acc.x += __shfl_xor(acc.x, off, 64);
            acc.y += __shfl_xor(acc.y, off, 64);
            acc.z += __shfl_xor(acc.z, off, 64);
            acc.w += __shfl_xor(acc.w, off, 64);
        }
        if (sub == 0) {
            float dv = __int_as_float(nb.z);
            float d2 = dv * dv;
            uint2 o;
            o.x = (uint)f2bf(acc.x * d2) | ((uint)f2bf(acc.y * d2) << 16);
            o.y = (uint)f2bf(acc.z * d2) | ((uint)f2bf(acc.w * d2) << 16);
            *(uint2*)(x2c + (size_t)wv * DIM + q * 4) = o;
        }
    }
}

// ---------- fused layer 3 + loss: wave per batch item -----------------------
__device__ __forceinline__ float x3_row(const ushort* __restrict__ x2c,
                                        const int* __restrict__ mapA,
                                        const int* __restrict__ csr_src,
                                        const int4* __restrict__ listB4,
                                        const int* __restrict__ mapB,
                                        int t, int lane) {
    int4 nb = listB4[mapB[t]];
    float acc = 0.f;
    for (int i = nb.x; i < nb.y; ++i) {
        int s = csr_src[i];
        int slot = mapA[s];
        acc += __uint_as_float((uint)x2c[(size_t)slot * DIM + lane] << 16);
    }
    return acc * __int_as_float(nb.z);
}

__global__ void k_loss(const float* __restrict__ emb, const ushort* __restrict__ x1c,
                       const ushort* __restrict__ x2c,
                       const int* __restrict__ mapA, const int* __restrict__ mapB,
                       const int4* __restrict__ listB4, const int* __restrict__ csr_src,
                       const float* __restrict__ dinv,
                       const int* __restrict__ u, const int* __restrict__ p,
                       const int* __restrict__ n, float* __restrict__ out) {
    int lane = threadIdx.x & 63;
    int w = (blockIdx.x * blockDim.x + threadIdx.x) >> 6;
    if (w >= BATCH) return;
    int ui = u[w], pi = p[w], ni = n[w];
    float dvu = dinv[ui], dvp = dinv[pi], dvn = dinv[ni];
    float rdu = dvu > 0.f ? 1.f / dvu : 0.f;
    float rdp = dvp > 0.f ? 1.f / dvp : 0.f;
    float rdn = dvn > 0.f ? 1.f / dvn : 0.f;
    float ue = emb[(size_t)ui * DIM + lane];
    float pe = emb[(size_t)pi * DIM + lane];
    float ne = emb[(size_t)ni * DIM + lane];
    float u1 = __uint_as_float((uint)x1c[(size_t)mapB[ui] * DIM + lane] << 16) * rdu;
    float p1 = __uint_as_float((uint)x1c[(size_t)mapB[pi] * DIM + lane] << 16) * rdp;
    float n1 = __uint_as_float((uint)x1c[(size_t)mapB[ni] * DIM + lane] << 16) * rdn;
    float u2 = __uint_as_float((uint)x2c[(size_t)mapA[ui] * DIM + lane] << 16) * rdu;
    float p2 = __uint_as_float((uint)x2c[(size_t)mapA[pi] * DIM + lane] << 16) * rdp;
    float n2 = __uint_as_float((uint)x2c[(size_t)mapA[ni] * DIM + lane] << 16) * rdn;
    float u3 = x3_row(x2c, mapA, csr_src, listB4, mapB, ui, lane);
    float p3 = x3_row(x2c, mapA, csr_src, listB4, mapB, pi, lane);
    float n3 = x3_row(x2c, mapA, csr_src, listB4, mapB, ni, lane);
    float uall = 0.25f * (ue + u1 + u2 + u3);
    float pall = 0.25f * (pe + p1 + p2 + p3);
    float nall = 0.25f * (ne + n1 + n2 + n3);
    float pos = uall * pall;
    float neg = uall * nall;
    float sq  = ue * ue + pe * pe + ne * ne;
    for (int off = 32; off; off >>= 1) {
        pos += __shfl_xor(pos, off, 64);
        neg += __shfl_xor(neg, off, 64);
        sq  += __shfl_xor(sq,  off, 64);
    }
    if (lane == 0) {
        float z = neg - pos;
        float sp = fmaxf(z, 0.0f) + log1pf(expf(-fabsf(z)));
        float contrib = sp * (1.0f / BATCH) + 1e-4f * 0.5f * sq * (1.0f / BATCH);
        atomicAdd(out, contrib);
    }
}

extern "C" void kernel_launch(void* const* d_in, const int* in_sizes, int n_in,
                              void* d_out, int out_size, void* d_ws, size_t ws_size,
                              hipStream_t stream) {
    const float* emb  = (const float*)d_in[0];
    const int*   edge = (const int*)d_in[1];
    const int*   src  = edge;
    const int*   dst  = edge + N_EDGES;
    const int*   uidx = (const int*)d_in[2];
    const int*   pidx = (const int*)d_in[3];
    const int*   nidx = (const int*)d_in[4];
    float* out = (float*)d_out;

    // ---- workspace layout (~150 MB) ----
    char* w = (char*)d_ws;
    ushort* embs    = (ushort*)w;                w += (size_t)N_NODES * DIM * 2;   // 64 MB
    ushort* x1c     = (ushort*)w;                w += (size_t)X1C_CAP * DIM * 2;   // 35.8 MB
    ushort* x2c     = (ushort*)w;                w += (size_t)LA_CAP * DIM * 2;    // 12.8 MB
    float*  dinv    = (float*)w;                 w += (size_t)N_NODES * 4;
    int*    rowstart= (int*)w;                   w += (size_t)N_NODES * 4;
    int*    csr_src = (int*)w;                   w += (size_t)N_EDGES * 4;
    int*    mapA    = (int*)w;                   w += (size_t)N_NODES * 4;
    int*    mapB    = (int*)w;                   w += (size_t)N_NODES * 4;
    int*    degsum  = (int*)w;                   w += (size_t)N_NODES * 4;
    int4*   listA4  = (int4*)w;                  w += (size_t)LA_CAP * 16;
    int4*   listB4  = (int4*)w;                  w += (size_t)X1C_CAP * 16;
    ushort* degp16  = (ushort*)w;                w += (size_t)HSLICES * RANGE_TOT * 2; // 8.1 MB, NOT zeroed (fully overwritten)
    // --- zeroed region (single memset): flags only ---
    char*   zbase   = w;
    uchar*  flags   = (uchar*)w;                 w += (size_t)3 * N_NODES;         // 1.5 MB
    uchar*  f3 = flags;
    uchar*  fA = flags + N_NODES;
    uchar*  fB = flags + 2 * N_NODES;
    size_t  zbytes  = (size_t)(w - zbase);
    int*    bsumD   = (int*)w;                   w += (size_t)NBLK * 4;
    int*    boffD   = (int*)w;                   w += (size_t)NBLK * 4;
    int*    bsumP   = (int*)w;                   w += (size_t)NBLK * 4;
    int*    boffA   = (int*)w;                   w += (size_t)NBLK * 4;
    int*    boffB   = (int*)w;                   w += (size_t)NBLK * 4;
    int*    counts  = (int*)w;                   w += 16;   // [0]=|fA|, [1]=|fB|

    hipMemsetAsync(zbase, 0, zbytes, stream);
    hipMemsetAsync(out, 0, 4, stream);

    // batch marks
    k_mark<<<(3 * BATCH + 255) / 256, 256, 0, stream>>>(uidx, pidx, nidx, f3, fA, fB);

    // LDS-range histogram (zero global atomics) || f3->fA expansion
    k_histexp<<<HIST_BLK + EDG4_BLK, 256, 0, stream>>>(src, dst, degp16, f3, fA);

    // fA -> fB
    k_expand<<<EDG4_BLK, 256, 0, stream>>>(src, dst, fA, fB);

    // fused scan trio: reduce degp16 + CSR offsets + dinv + maps + worklists
    k_scanA<<<NBLK, SCAN_B, 0, stream>>>(degp16, fA, fB, degsum, bsumD, bsumP);
    k_scanB<<<1, 512, 0, stream>>>(bsumD, bsumP, boffD, boffA, boffB, counts);
    k_scanC<<<NBLK, SCAN_B, 0, stream>>>(degsum, fA, fB, boffD, boffA, boffB,
                                         rowstart, dinv, mapA, mapB, listA4, listB4);

    // INTERLEAVED: masked CSR fill (fabric atomics) || pre-scaled bf16 staging
    k_convscatter<<<CS_TOTAL, 256, 0, stream>>>(
        emb, dinv, embs, src, dst, fB, rowstart, csr_src);

    // sparse propagation (persistent grid-stride)
    k_prop1<<<PROP_BLK, 256, 0, stream>>>(embs, listB4, counts, csr_src, x1c);
    k_prop2<<<PROP_BLK, 256, 0, stream>>>(x1c, mapB, listA4, counts, csr_src, x2c);

    // fused layer-3 + loss
    k_loss<<<(BATCH * 64 + 255) / 256, 256, 0, stream>>>(
        emb, x1c, x2c, mapA, mapB, listB4, csr_src, dinv, uidx, pidx, nidx, out);
}

// Round 6
// 428.672 us; speedup vs baseline: 1.1357x; 1.1357x over previous
//
#include <hip/hip_runtime.h>
#include <cstdint>
#include <cstddef>

#define N_USERS   100000
#define N_NODES   500000
#define DIM       64
#define N_EDGES   2000000
#define BATCH     4096
#define SCAN_B    1024
#define NBLK      ((N_NODES + SCAN_B - 1) / SCAN_B)   // 489
#define X1C_CAP   280000   // |fB| ~230k measured
#define LA_CAP    100000   // |fA| ~60k measured
#define EDG4_BLK  ((N_EDGES / 4 + 255) / 256)         // 1954 blocks, 4 edges/thread
#define CONV_BLK  ((N_NODES * 16 + 255) / 256)        // 31250 conv blocks
#define CS_TOTAL  (EDG4_BLK * 17)                     // 33218: 1 scatter per 16 conv
#define PROP_BLK  2048                                // 8192 waves = 32/CU

// ---- LDS histogram geometry v2 (8-bit counters, 8x parallelism) ----
#define RANGES    31
#define RANGE_SZ  16384                               // nodes per range
#define RANGE_TOT (RANGES * RANGE_SZ)                 // 507904 >= N_NODES
#define HSLICES   32
#define HIST_BLK  (RANGES * HSLICES)                  // 992
#define ESLICE    (N_EDGES / HSLICES)                 // 62500
#define EINT4     (ESLICE / 4)                        // 15625

typedef unsigned char uchar;
typedef unsigned short ushort;
typedef unsigned int uint;

__device__ __forceinline__ ushort f2bf(float f) {
    uint u = __float_as_uint(f);
    uint r = u + 0x7FFFu + ((u >> 16) & 1u);
    return (ushort)(r >> 16);
}
__device__ __forceinline__ float bflo(uint u) { return __uint_as_float(u << 16); }
__device__ __forceinline__ float bfhi(uint u) { return __uint_as_float(u & 0xFFFF0000u); }

// ---------- mark batch indices into three byte flags ------------------------
__global__ void k_mark(const int* __restrict__ u, const int* __restrict__ p,
                       const int* __restrict__ n, uchar* __restrict__ f3,
                       uchar* __restrict__ fA, uchar* __restrict__ fB) {
    int i = blockIdx.x * blockDim.x + threadIdx.x;
    if (i >= 3 * BATCH) return;
    int idx;
    if (i < BATCH)          idx = u[i];
    else if (i < 2 * BATCH) idx = p[i - BATCH];
    else                    idx = n[i - 2 * BATCH];
    f3[idx] = 1; fA[idx] = 1; fB[idx] = 1;
}

// ---------- expand fin -> fout (dedup writes, 4 edges/thread) ---------------
// Used standalone for level-1 (f3 -> fA); level-2 rides inside k_histexp.
__global__ void k_expand(const int* __restrict__ src, const int* __restrict__ dst,
                         const uchar* __restrict__ fin, uchar* __restrict__ fout) {
    int t = blockIdx.x * blockDim.x + threadIdx.x;
    if (t < N_EDGES / 4) {
        int4 s0 = ((const int4*)src)[t];
        int4 d0 = ((const int4*)dst)[t];
        if (fin[d0.x] && !fout[s0.x]) fout[s0.x] = 1;
        if (fin[d0.y] && !fout[s0.y]) fout[s0.y] = 1;
        if (fin[d0.z] && !fout[s0.z]) fout[s0.z] = 1;
        if (fin[d0.w] && !fout[s0.w]) fout[s0.w] = 1;
    }
}

// ---------- fused: LDS-range histogram (8-bit) + fA -> fB expansion ---------
// R5 failure mode: only 248 hist blocks -> 14.8% occupancy tail. v2: 8-bit
// counters (per-slice per-node count << 255) -> 16 KB LDS -> 992 hist blocks,
// slice-major order so the 31 co-resident blocks of a slice share L2 lines.
// The histogram needs only dst, NOT fA -> it overlaps the level-2 expansion
// instead of the level-1 (which now runs before as its own kernel).
__global__ void k_histexp(const int* __restrict__ src, const int* __restrict__ dst,
                          uchar* __restrict__ degp8, const uchar* __restrict__ fA,
                          uchar* __restrict__ fB) {
    __shared__ uint cnt[RANGE_SZ / 4];            // 4096 words = 16 KB
    if (blockIdx.x < HIST_BLK) {
        int s = blockIdx.x / RANGES;              // slice 0..31 (slice-major)
        int r = blockIdx.x - s * RANGES;          // range 0..30
        for (int k = threadIdx.x; k < RANGE_SZ / 4; k += 256) cnt[k] = 0;
        __syncthreads();
        int base = r * RANGE_SZ;
        const int4* d4 = (const int4*)(dst + s * ESLICE);
        for (int t = threadIdx.x; t < EINT4; t += 256) {
            int4 d = d4[t];
            uint l;
            l = (uint)(d.x - base); if (l < RANGE_SZ) atomicAdd(&cnt[l >> 2], 1u << ((l & 3) << 3));
            l = (uint)(d.y - base); if (l < RANGE_SZ) atomicAdd(&cnt[l >> 2], 1u << ((l & 3) << 3));
            l = (uint)(d.z - base); if (l < RANGE_SZ) atomicAdd(&cnt[l >> 2], 1u << ((l & 3) << 3));
            l = (uint)(d.w - base); if (l < RANGE_SZ) atomicAdd(&cnt[l >> 2], 1u << ((l & 3) << 3));
        }
        __syncthreads();
        uint* out = (uint*)(degp8 + (size_t)s * RANGE_TOT) + r * (RANGE_SZ / 4);
        for (int k = threadIdx.x; k < RANGE_SZ / 4; k += 256) out[k] = cnt[k];
    } else {
        int t = (blockIdx.x - HIST_BLK) * blockDim.x + threadIdx.x;
        if (t < N_EDGES / 4) {
            int4 s0 = ((const int4*)src)[t];
            int4 d0 = ((const int4*)dst)[t];
            if (fA[d0.x] && !fB[s0.x]) fB[s0.x] = 1;
            if (fA[d0.y] && !fB[s0.y]) fB[s0.y] = 1;
            if (fA[d0.z] && !fB[s0.z]) fB[s0.z] = 1;
            if (fA[d0.w] && !fB[s0.w]) fB[s0.w] = 1;
        }
    }
}

// ---------- scan A: reduce 32 degp8 slices -> degsum; block sums ------------
__global__ void k_scanA(const uchar* __restrict__ degp8, const uchar* __restrict__ fA,
                        const uchar* __restrict__ fB, int* __restrict__ degsum,
                        int* __restrict__ bsumD, int* __restrict__ bsumP) {
    __shared__ int sD[SCAN_B];
    __shared__ int sP[SCAN_B];
    int i = blockIdx.x * SCAN_B + threadIdx.x;
    int d = 0, pk = 0;
    if (i < N_NODES) {
        #pragma unroll
        for (int s = 0; s < HSLICES; ++s) d += (int)degp8[(size_t)s * RANGE_TOT + i];
        degsum[i] = d;
        pk = (int)fA[i] | ((int)fB[i] << 16);
    }
    sD[threadIdx.x] = d; sP[threadIdx.x] = pk;
    __syncthreads();
    for (int off = SCAN_B / 2; off; off >>= 1) {
        if (threadIdx.x < off) {
            sD[threadIdx.x] += sD[threadIdx.x + off];
            sP[threadIdx.x] += sP[threadIdx.x + off];
        }
        __syncthreads();
    }
    if (threadIdx.x == 0) { bsumD[blockIdx.x] = sD[0]; bsumP[blockIdx.x] = sP[0]; }
}

// ---------- scan B: exclusive scans of block sums ---------------------------
__global__ void k_scanB(const int* __restrict__ bsumD, const int* __restrict__ bsumP,
                        int* __restrict__ boffD, int* __restrict__ boffA,
                        int* __restrict__ boffB, int* __restrict__ counts) {
    __shared__ int sD[512];
    __shared__ int sA[512];
    __shared__ int sB[512];
    int d = (threadIdx.x < NBLK) ? bsumD[threadIdx.x] : 0;
    int p = (threadIdx.x < NBLK) ? bsumP[threadIdx.x] : 0;
    int a = p & 0xFFFF, b = p >> 16;
    sD[threadIdx.x] = d; sA[threadIdx.x] = a; sB[threadIdx.x] = b;
    __syncthreads();
    for (int off = 1; off < 512; off <<= 1) {
        int tD = (threadIdx.x >= off) ? sD[threadIdx.x - off] : 0;
        int tA = (threadIdx.x >= off) ? sA[threadIdx.x - off] : 0;
        int tB = (threadIdx.x >= off) ? sB[threadIdx.x - off] : 0;
        __syncthreads();
        sD[threadIdx.x] += tD; sA[threadIdx.x] += tA; sB[threadIdx.x] += tB;
        __syncthreads();
    }
    if (threadIdx.x < NBLK) {
        boffD[threadIdx.x] = sD[threadIdx.x] - d;
        boffA[threadIdx.x] = sA[threadIdx.x] - a;
        boffB[threadIdx.x] = sB[threadIdx.x] - b;
    }
    if (threadIdx.x == 511) { counts[0] = sA[511]; counts[1] = sB[511]; }
}

// ---------- scan C: rowstart/dinv + mapA/mapB + packed worklists ------------
__global__ void k_scanC(const int* __restrict__ degsum, const uchar* __restrict__ fA,
                        const uchar* __restrict__ fB,
                        const int* __restrict__ boffD, const int* __restrict__ boffA,
                        const int* __restrict__ boffB,
                        int* __restrict__ rowstart, float* __restrict__ dinv,
                        int* __restrict__ mapA, int* __restrict__ mapB,
                        int4* __restrict__ listA4, int4* __restrict__ listB4) {
    __shared__ int sD[SCAN_B];
    __shared__ int sP[SCAN_B];
    int i = blockIdx.x * SCAN_B + threadIdx.x;
    int d = 0, a = 0, b = 0;
    if (i < N_NODES) { d = degsum[i]; a = (int)fA[i]; b = (int)fB[i]; }
    sD[threadIdx.x] = d; sP[threadIdx.x] = a | (b << 16);
    __syncthreads();
    for (int off = 1; off < SCAN_B; off <<= 1) {
        int tD = (threadIdx.x >= off) ? sD[threadIdx.x - off] : 0;
        int tP = (threadIdx.x >= off) ? sP[threadIdx.x - off] : 0;
        __syncthreads();
        sD[threadIdx.x] += tD; sP[threadIdx.x] += tP;
        __syncthreads();
    }
    if (i < N_NODES) {
        int exD = sD[threadIdx.x] - d + boffD[blockIdx.x];
        int incP = sP[threadIdx.x];
        int exA = (incP & 0xFFFF) - a + boffA[blockIdx.x];
        int exB = (incP >> 16) - b + boffB[blockIdx.x];
        rowstart[i] = exD;
        float dv = (d > 0) ? rsqrtf((float)d) : 0.0f;
        dinv[i] = dv;
        mapA[i] = a ? exA : -1;
        mapB[i] = b ? exB : -1;
        int4 ent = make_int4(exD, exD + d, __float_as_int(dv), 0);
        if (a) listA4[exA] = ent;
        if (b) listB4[exB] = ent;
    }
}

// ---------- INTERLEAVED conv + scatter --------------------------------------
// Groups of 17 blocks: slot 8 is a scatter block, the other 16 are conv.
__global__ void k_convscatter(const float* __restrict__ emb,
                              const float* __restrict__ dinv,
                              ushort* __restrict__ embs,
                              const int* __restrict__ src, const int* __restrict__ dst,
                              const uchar* __restrict__ fB,
                              int* __restrict__ rowstart, int* __restrict__ csr_src) {
    uint b = blockIdx.x;
    uint g = b / 17u;
    uint r = b - g * 17u;
    if (r == 8u) {                       // scatter block, index g in [0, EDG4_BLK)
        int t = (int)g * blockDim.x + threadIdx.x;
        if (t < N_EDGES / 4) {
            int4 s0 = ((const int4*)src)[t];
            int4 d0 = ((const int4*)dst)[t];
            if (fB[d0.x]) csr_src[atomicAdd(&rowstart[d0.x], 1)] = s0.x;
            if (fB[d0.y]) csr_src[atomicAdd(&rowstart[d0.y], 1)] = s0.y;
            if (fB[d0.z]) csr_src[atomicAdd(&rowstart[d0.z], 1)] = s0.z;
            if (fB[d0.w]) csr_src[atomicAdd(&rowstart[d0.w], 1)] = s0.w;
        }
    } else {                             // conv block
        uint convblk = g * 16u + r - (r > 8u ? 1u : 0u);
        int c = (int)convblk * blockDim.x + threadIdx.x;   // 4-float chunk
        if (c < N_NODES * 16) {
            int row = c >> 4;
            float4 v = ((const float4*)emb)[c];
            float dv = dinv[row];
            uint2 o;
            o.x = (uint)f2bf(v.x * dv) | ((uint)f2bf(v.y * dv) << 16);
            o.y = (uint)f2bf(v.z * dv) | ((uint)f2bf(v.w * dv) << 16);
            ((uint2*)embs)[c] = o;
        }
    }
}

// ---------- layer 1: embs(bf16, pre-scaled) -> x1c(bf16, x1*dinv[node]) -----
__global__ void k_prop1(const ushort* __restrict__ embs, const int4* __restrict__ listB4,
                        const int* __restrict__ counts, const int* __restrict__ csr_src,
                        ushort* __restrict__ x1c) {
    int lane = threadIdx.x & 63;
    int sub = lane >> 4, q = lane & 15;
    int wv = (blockIdx.x * blockDim.x + threadIdx.x) >> 6;
    int nw = (gridDim.x * blockDim.x) >> 6;
    int cnt = counts[1];
    for (; wv < cnt; wv += nw) {
        int4 nb = listB4[wv];
        float4 acc = {0.f, 0.f, 0.f, 0.f};
        for (int i = nb.x + sub; i < nb.y; i += 4) {
            int s = csr_src[i];
            uint2 u = *(const uint2*)(embs + (size_t)s * DIM + q * 4);
            acc.x += bflo(u.x); acc.y += bfhi(u.x);
            acc.z += bflo(u.y); acc.w += bfhi(u.y);
        }
        for (int off = 16; off <= 32; off <<= 1) {
            acc.x += __shfl_xor(acc.x, off, 64);
            acc.y += __shfl_xor(acc.y, off, 64);
            acc.z += __shfl_xor(acc.z, off, 64);
            acc.w += __shfl_xor(acc.w, off, 64);
        }
        if (sub == 0) {
            float dv = __int_as_float(nb.z);
            float d2 = dv * dv;   // store x1*dinv[node] for next layer
            uint2 o;
            o.x = (uint)f2bf(acc.x * d2) | ((uint)f2bf(acc.y * d2) << 16);
            o.y = (uint)f2bf(acc.z * d2) | ((uint)f2bf(acc.w * d2) << 16);
            *(uint2*)(x1c + (size_t)wv * DIM + q * 4) = o;
        }
    }
}

// ---------- layer 2: x1c -> x2c (bf16, x2*dinv[node]) -----------------------
__global__ void k_prop2(const ushort* __restrict__ x1c, const int* __restrict__ mapB,
                        const int4* __restrict__ listA4, const int* __restrict__ counts,
                        const int* __restrict__ csr_src, ushort* __restrict__ x2c) {
    int lane = threadIdx.x & 63;
    int sub = lane >> 4, q = lane & 15;
    int wv = (blockIdx.x * blockDim.x + threadIdx.x) >> 6;
    int nw = (gridDim.x * blockDim.x) >> 6;
    int cnt = counts[0];
    for (; wv < cnt; wv += nw) {
        int4 nb = listA4[wv];
        float4 acc = {0.f, 0.f, 0.f, 0.f};
        for (int i = nb.x + sub; i < nb.y; i += 4) {
            int s = csr_src[i];
            int slot = mapB[s];
            uint2 u = *(const uint2*)(x1c + (size_t)slot * DIM + q * 4);
            acc.x += bflo(u.x); acc.y += bfhi(u.x);
            acc.z += bflo(u.y); acc.w += bfhi(u.y);
        }
        for (int off = 16; off <= 32; off <<= 1) {
            acc.x += __shfl_xor(acc.x, off, 64);
            acc.y += __shfl_xor(acc.y, off, 64);
            acc.z += __shfl_xor(acc.z, off, 64);
            acc.w += __shfl_xor(acc.w, off, 64);
        }
        if (sub == 0) {
            float dv = __int_as_float(nb.z);
            float d2 = dv * dv;
            uint2 o;
            o.x = (uint)f2bf(acc.x * d2) | ((uint)f2bf(acc.y * d2) << 16);
            o.y = (uint)f2bf(acc.z * d2) | ((uint)f2bf(acc.w * d2) << 16);
            *(uint2*)(x2c + (size_t)wv * DIM + q * 4) = o;
        }
    }
}

// ---------- fused layer 3 + loss: wave per batch item -----------------------
__device__ __forceinline__ float x3_row(const ushort* __restrict__ x2c,
                                        const int* __restrict__ mapA,
                                        const int* __restrict__ csr_src,
                                        const int4* __restrict__ listB4,
                                        const int* __restrict__ mapB,
                                        int t, int lane) {
    int4 nb = listB4[mapB[t]];
    float acc = 0.f;
    for (int i = nb.x; i < nb.y; ++i) {
        int s = csr_src[i];
        int slot = mapA[s];
        acc += __uint_as_float((uint)x2c[(size_t)slot * DIM + lane] << 16);
    }
    return acc * __int_as_float(nb.z);
}

__global__ void k_loss(const float* __restrict__ emb, const ushort* __restrict__ x1c,
                       const ushort* __restrict__ x2c,
                       const int* __restrict__ mapA, const int* __restrict__ mapB,
                       const int4* __restrict__ listB4, const int* __restrict__ csr_src,
                       const float* __restrict__ dinv,
                       const int* __restrict__ u, const int* __restrict__ p,
                       const int* __restrict__ n, float* __restrict__ out) {
    int lane = threadIdx.x & 63;
    int w = (blockIdx.x * blockDim.x + threadIdx.x) >> 6;
    if (w >= BATCH) return;
    int ui = u[w], pi = p[w], ni = n[w];
    float dvu = dinv[ui], dvp = dinv[pi], dvn = dinv[ni];
    float rdu = dvu > 0.f ? 1.f / dvu : 0.f;
    float rdp = dvp > 0.f ? 1.f / dvp : 0.f;
    float rdn = dvn > 0.f ? 1.f / dvn : 0.f;
    float ue = emb[(size_t)ui * DIM + lane];
    float pe = emb[(size_t)pi * DIM + lane];
    float ne = emb[(size_t)ni * DIM + lane];
    float u1 = __uint_as_float((uint)x1c[(size_t)mapB[ui] * DIM + lane] << 16) * rdu;
    float p1 = __uint_as_float((uint)x1c[(size_t)mapB[pi] * DIM + lane] << 16) * rdp;
    float n1 = __uint_as_float((uint)x1c[(size_t)mapB[ni] * DIM + lane] << 16) * rdn;
    float u2 = __uint_as_float((uint)x2c[(size_t)mapA[ui] * DIM + lane] << 16) * rdu;
    float p2 = __uint_as_float((uint)x2c[(size_t)mapA[pi] * DIM + lane] << 16) * rdp;
    float n2 = __uint_as_float((uint)x2c[(size_t)mapA[ni] * DIM + lane] << 16) * rdn;
    float u3 = x3_row(x2c, mapA, csr_src, listB4, mapB, ui, lane);
    float p3 = x3_row(x2c, mapA, csr_src, listB4, mapB, pi, lane);
    float n3 = x3_row(x2c, mapA, csr_src, listB4, mapB, ni, lane);
    float uall = 0.25f * (ue + u1 + u2 + u3);
    float pall = 0.25f * (pe + p1 + p2 + p3);
    float nall = 0.25f * (ne + n1 + n2 + n3);
    float pos = uall * pall;
    float neg = uall * nall;
    float sq  = ue * ue + pe * pe + ne * ne;
    for (int off = 32; off; off >>= 1) {
        pos += __shfl_xor(pos, off, 64);
        neg += __shfl_xor(neg, off, 64);
        sq  += __shfl_xor(sq,  off, 64);
    }
    if (lane == 0) {
        float z = neg - pos;
        float sp = fmaxf(z, 0.0f) + log1pf(expf(-fabsf(z)));
        float contrib = sp * (1.0f / BATCH) + 1e-4f * 0.5f * sq * (1.0f / BATCH);
        atomicAdd(out, contrib);
    }
}

extern "C" void kernel_launch(void* const* d_in, const int* in_sizes, int n_in,
                              void* d_out, int out_size, void* d_ws, size_t ws_size,
                              hipStream_t stream) {
    const float* emb  = (const float*)d_in[0];
    const int*   edge = (const int*)d_in[1];
    const int*   src  = edge;
    const int*   dst  = edge + N_EDGES;
    const int*   uidx = (const int*)d_in[2];
    const int*   pidx = (const int*)d_in[3];
    const int*   nidx = (const int*)d_in[4];
    float* out = (float*)d_out;

    // ---- workspace layout (~155 MB) ----
    char* w = (char*)d_ws;
    ushort* embs    = (ushort*)w;                w += (size_t)N_NODES * DIM * 2;   // 64 MB
    ushort* x1c     = (ushort*)w;                w += (size_t)X1C_CAP * DIM * 2;   // 35.8 MB
    ushort* x2c     = (ushort*)w;                w += (size_t)LA_CAP * DIM * 2;    // 12.8 MB
    float*  dinv    = (float*)w;                 w += (size_t)N_NODES * 4;
    int*    rowstart= (int*)w;                   w += (size_t)N_NODES * 4;
    int*    csr_src = (int*)w;                   w += (size_t)N_EDGES * 4;
    int*    mapA    = (int*)w;                   w += (size_t)N_NODES * 4;
    int*    mapB    = (int*)w;                   w += (size_t)N_NODES * 4;
    int*    degsum  = (int*)w;                   w += (size_t)N_NODES * 4;
    int4*   listA4  = (int4*)w;                  w += (size_t)LA_CAP * 16;
    int4*   listB4  = (int4*)w;                  w += (size_t)X1C_CAP * 16;
    uchar*  degp8   = (uchar*)w;                 w += (size_t)HSLICES * RANGE_TOT; // 15.5 MB, NOT zeroed (fully overwritten)
    // --- zeroed region (single memset): flags only ---
    char*   zbase   = w;
    uchar*  flags   = (uchar*)w;                 w += (size_t)3 * N_NODES;         // 1.5 MB
    uchar*  f3 = flags;
    uchar*  fA = flags + N_NODES;
    uchar*  fB = flags + 2 * N_NODES;
    size_t  zbytes  = (size_t)(w - zbase);
    int*    bsumD   = (int*)w;                   w += (size_t)NBLK * 4;
    int*    boffD   = (int*)w;                   w += (size_t)NBLK * 4;
    int*    bsumP   = (int*)w;                   w += (size_t)NBLK * 4;
    int*    boffA   = (int*)w;                   w += (size_t)NBLK * 4;
    int*    boffB   = (int*)w;                   w += (size_t)NBLK * 4;
    int*    counts  = (int*)w;                   w += 16;   // [0]=|fA|, [1]=|fB|

    hipMemsetAsync(zbase, 0, zbytes, stream);
    hipMemsetAsync(out, 0, 4, stream);

    // batch marks
    k_mark<<<(3 * BATCH + 255) / 256, 256, 0, stream>>>(uidx, pidx, nidx, f3, fA, fB);

    // level-1 expansion (f3 -> fA) — needs only f3
    k_expand<<<EDG4_BLK, 256, 0, stream>>>(src, dst, f3, fA);

    // LDS-range histogram (needs only dst) || level-2 expansion (fA -> fB)
    k_histexp<<<HIST_BLK + EDG4_BLK, 256, 0, stream>>>(src, dst, degp8, fA, fB);

    // fused scan trio: reduce degp8 + CSR offsets + dinv + maps + worklists
    k_scanA<<<NBLK, SCAN_B, 0, stream>>>(degp8, fA, fB, degsum, bsumD, bsumP);
    k_scanB<<<1, 512, 0, stream>>>(bsumD, bsumP, boffD, boffA, boffB, counts);
    k_scanC<<<NBLK, SCAN_B, 0, stream>>>(degsum, fA, fB, boffD, boffA, boffB,
                                         rowstart, dinv, mapA, mapB, listA4, listB4);

    // INTERLEAVED: masked CSR fill (fabric atomics) || pre-scaled bf16 staging
    k_convscatter<<<CS_TOTAL, 256, 0, stream>>>(
        emb, dinv, embs, src, dst, fB, rowstart, csr_src);

    // sparse propagation (persistent grid-stride)
    k_prop1<<<PROP_BLK, 256, 0, stream>>>(embs, listB4, counts, csr_src, x1c);
    k_prop2<<<PROP_BLK, 256, 0, stream>>>(x1c, mapB, listA4, counts, csr_src, x2c);

    // fused layer-3 + loss
    k_loss<<<(BATCH * 64 + 255) / 256, 256, 0, stream>>>(
        emb, x1c, x2c, mapA, mapB, listB4, csr_src, dinv, uidx, pidx, nidx, out);
}